// Round 7
// baseline (331.887 us; speedup 1.0000x reference)
//
#include <hip/hip_runtime.h>
#include <stdint.h>

#define BB 4
#define SS 2048
#define DD 1024
#define HH 16
#define DKK 64

typedef unsigned short u16;
typedef short s16x8 __attribute__((ext_vector_type(8)));
typedef float f32x4 __attribute__((ext_vector_type(4)));

__device__ __forceinline__ void async_copy16(const void* g, void* l) {
  __builtin_amdgcn_global_load_lds(
      (const __attribute__((address_space(1))) void*)g,
      (__attribute__((address_space(3))) void*)l, 16, 0, 0);
}

__device__ __forceinline__ u16 f2bf(float f) {
  union { float f; uint32_t u; } x; x.f = f;
  uint32_t r = x.u + 0x7fffu + ((x.u >> 16) & 1u);
  return (u16)(r >> 16);
}

// packed RNE f32x2 -> bf16x2 (hardware)
__device__ __forceinline__ uint32_t cvtpk(float a, float b) {
  uint32_t d;
  asm("v_cvt_pk_bf16_f32 %0, %1, %2" : "=v"(d) : "v"(a), "v"(b));
  return d;
}

// lane ^ 16 exchange (within each 32-lane half)
__device__ __forceinline__ uint32_t swz16(uint32_t x) {
  return (uint32_t)__builtin_amdgcn_ds_swizzle((int)x, 0x401F);
}

// One-shot fp32 -> bf16 convert of xq,xk,xv then Wq,Wk,Wv,Wo into ws.
__global__ __launch_bounds__(256) void cvt_kernel(
    const float* __restrict__ x0, const float* __restrict__ x1,
    const float* __restrict__ x2, const float* __restrict__ w0,
    const float* __restrict__ w1, const float* __restrict__ w2,
    const float* __restrict__ w3, u16* __restrict__ dst) {
  const size_t base = ((size_t)blockIdx.x * 256 + threadIdx.x) * 8;
  const float* src;
  size_t off;
  if (base < 25165824ull) {
    const size_t t = base >> 23;
    src = (t == 0) ? x0 : (t == 1) ? x1 : x2;
    off = base & 8388607ull;
  } else {
    const size_t r = base - 25165824ull;
    const size_t t = r >> 20;
    src = (t == 0) ? w0 : (t == 1) ? w1 : (t == 2) ? w2 : w3;
    off = r & 1048575ull;
  }
  const float4 a = *(const float4*)(src + off);
  const float4 b = *(const float4*)(src + off + 4);
  s16x8 o;
  o[0] = (short)f2bf(a.x); o[1] = (short)f2bf(a.y);
  o[2] = (short)f2bf(a.z); o[3] = (short)f2bf(a.w);
  o[4] = (short)f2bf(b.x); o[5] = (short)f2bf(b.y);
  o[6] = (short)f2bf(b.z); o[7] = (short)f2bf(b.w);
  *(s16x8*)(dst + base) = o;
}

// C[M,N] = A[M,K] @ W[N,K]^T, fp32 accum, chunk-XOR-swizzled LDS (conflict-free
// b128 frag reads). seg = blockIdx.y. If seg == vt_seg, epilogue writes output
// transposed per-head: VT[b][h][d][s] (ushort4 = 4 contiguous tokens), else
// row-major (bf16 or fp32 per OUT_F32).
// T1 XCD swizzle: 512 x-blocks, 8 XCDs -> swz groups 64 consecutive tiles per
// XCD so the 2MB W-panel is reused 64x and each A-tile 8x within one L2.
template <bool IN_F32, bool OUT_F32>
__global__ __launch_bounds__(256, 3) void gemm_bt(
    const void* __restrict__ Ap, const void* __restrict__ Bp, void* __restrict__ Cp,
    size_t asegstride, size_t bsegstride, size_t csegstride, int vt_seg) {
  const int K = 1024, N = 1024;
  __shared__ u16 Alds[128 * 64];
  __shared__ u16 Blds[128 * 64];
  const int tid = threadIdx.x;
  const int wid = tid >> 6, lane = tid & 63;
  const int quad = lane >> 4, l16 = lane & 15;
  const int bidx = blockIdx.x;
  const int swz = ((bidx & 7) << 6) | (bidx >> 3);   // bijective, 512 % 8 == 0
  const int mtile = swz >> 3;
  const int ntile = swz & 7;
  const int wm = wid >> 1, wn = wid & 1;
  const int seg = blockIdx.y;
  f32x4 acc[4][4] = {};
  for (int kb = 0; kb < K; kb += 64) {
    if constexpr (IN_F32) {
      const float* Af = (const float*)Ap + seg * asegstride + (size_t)mtile * 128 * K;
      const float* Bf = (const float*)Bp + seg * bsegstride + (size_t)ntile * 128 * K;
#pragma unroll
      for (int i = 0; i < 8; ++i) {
        const int c = i * 256 + tid;
        const int row = c >> 4, g = c & 15;
        const int cc = g >> 1, h = g & 1;
        const int sl = row * 8 + (cc ^ (row & 7));
        {
          const float4 v = *(const float4*)(Af + (size_t)row * K + kb + g * 4);
          ushort4 o;
          o.x = f2bf(v.x); o.y = f2bf(v.y); o.z = f2bf(v.z); o.w = f2bf(v.w);
          *(ushort4*)&Alds[sl * 8 + h * 4] = o;
        }
        {
          const float4 v = *(const float4*)(Bf + (size_t)row * K + kb + g * 4);
          ushort4 o;
          o.x = f2bf(v.x); o.y = f2bf(v.y); o.z = f2bf(v.z); o.w = f2bf(v.w);
          *(ushort4*)&Blds[sl * 8 + h * 4] = o;
        }
      }
    } else {
      const u16* Ab = (const u16*)Ap + seg * asegstride + (size_t)mtile * 128 * K;
      const u16* Bb = (const u16*)Bp + seg * bsegstride + (size_t)ntile * 128 * K;
#pragma unroll
      for (int i = 0; i < 4; ++i) {
        const int s = i * 256 + tid;
        const int row = s >> 3;
        const int cc = (s & 7) ^ (row & 7);
        async_copy16(Ab + (size_t)row * K + kb + cc * 8,
                     (char*)Alds + (i * 256 + wid * 64) * 16);
        async_copy16(Bb + (size_t)row * K + kb + cc * 8,
                     (char*)Blds + (i * 256 + wid * 64) * 16);
      }
    }
    __syncthreads();
#pragma unroll
    for (int ks = 0; ks < 2; ++ks) {
      s16x8 af[4], bfr[4];
#pragma unroll
      for (int i = 0; i < 4; ++i) {
        const int R = wm * 64 + i * 16 + l16;
        af[i] = *(const s16x8*)&Alds[(R * 8 + ((ks * 4 + quad) ^ (l16 & 7))) * 8];
      }
#pragma unroll
      for (int j = 0; j < 4; ++j) {
        const int R = wn * 64 + j * 16 + l16;
        bfr[j] = *(const s16x8*)&Blds[(R * 8 + ((ks * 4 + quad) ^ (l16 & 7))) * 8];
      }
#pragma unroll
      for (int i = 0; i < 4; ++i)
#pragma unroll
        for (int j = 0; j < 4; ++j)
          acc[i][j] = __builtin_amdgcn_mfma_f32_16x16x32_bf16(af[i], bfr[j], acc[i][j], 0, 0, 0);
    }
    __syncthreads();
  }
  const int row0 = mtile * 128 + wm * 64 + quad * 4;
  const int col0 = ntile * 128 + wn * 64 + l16;
  if (seg == vt_seg) {
    // V^T epilogue: element (token, col) -> VT[(b*16+h)*64+d][s], d=col&63.
    u16* VT = (u16*)Cp + (size_t)seg * csegstride;
#pragma unroll
    for (int i = 0; i < 4; ++i)
#pragma unroll
      for (int j = 0; j < 4; ++j) {
        const int col = col0 + j * 16;
        const int row = row0 + i * 16;
        const int bb = row >> 11, s0 = row & 2047;
        const size_t dst = (((size_t)bb * HH + (col >> 6)) * DKK + (col & 63)) * SS + s0;
        ushort4 o;
        o.x = f2bf(acc[i][j][0]); o.y = f2bf(acc[i][j][1]);
        o.z = f2bf(acc[i][j][2]); o.w = f2bf(acc[i][j][3]);
        *(ushort4*)(VT + dst) = o;
      }
  } else {
#pragma unroll
    for (int i = 0; i < 4; ++i)
#pragma unroll
      for (int j = 0; j < 4; ++j)
#pragma unroll
        for (int r = 0; r < 4; ++r) {
          const size_t idx = (size_t)(row0 + i * 16 + r) * N + col0 + j * 16;
          if constexpr (OUT_F32) ((float*)Cp)[seg * csegstride + idx] = acc[i][j][r];
          else                   ((u16*)Cp)[seg * csegstride + idx] = f2bf(acc[i][j][r]);
        }
  }
}

// Flash attention: 128 q-rows/block, 4 waves x 32 q-rows, swapped QK^T (T12)
// with fully in-register P redistribution (verified R4 structure, 0 bank
// conflicts). V pre-transposed per-head VT[b][h][d][s]. No-max softmax via
// exp2, l via ones-MFMA. Split-K (MODE 1) combines by pure addition.
// NEW (T14/T3-lite): K/V LDS double-buffered; next tile's global_load_lds
// issued BEFORE compute; "s_waitcnt vmcnt(4); s_barrier" fused at top of step
// (own prefetch stays in flight, everyone's current tile proven landed);
// raw s_barrier (no vmcnt drain) at step end. Bias from per-lane mask loads
// (L1-broadcast) instead of an LDS round-trip. LDS 33 KB -> 4 blocks/CU.
template <int MODE>
__global__ __launch_bounds__(256, 4) void attn_kernel(
    const u16* __restrict__ Q, const u16* __restrict__ K, const u16* __restrict__ VT,
    const int* __restrict__ mask, u16* __restrict__ O,
    float* __restrict__ Opart, float* __restrict__ lpart) {
  __shared__ u16 Klds[2][64 * 64];  // swizzled [key][d], double-buffered
  __shared__ u16 Vt[2][64 * 64];    // swizzled [d][key], double-buffered
  const int bid = blockIdx.x;
  int qt, kt0, kt1, code, bh;
  if constexpr (MODE == 0) {
    qt = 15 - (bid >> 6);          // heavy tiles first
    bh = bid & 63;
    code = 2;                      // always full tile
    kt0 = 0; kt1 = 2 * qt + 2;
  } else {
    bh = bid & 63;
    const int w = bid >> 6;        // 0..23, heavy-first work items
    const int wsel = w >> 3, wo = w & 7;
    // qt nibbles, low-first: {15,15,7,14,14,6,13,13|12,12,5,11,11,10,10,4|9,9,8,8,3,2,1,0}
    const uint32_t qw = (wsel == 0) ? 0xDD6EE7FFu : (wsel == 1) ? 0x4AABB5CCu : 0x01238899u;
    // split codes (2b): 0=first half, 1=second half, 2=full tile
    const uint32_t sw = (wsel == 0) ? 0x4924u : (wsel == 1) ? 0x9124u : 0xAA44u;
    qt = (int)((qw >> (wo * 4)) & 15u);
    code = (int)((sw >> (wo * 2)) & 3u);
    const int half = qt + 1;       // ktiles = 2qt+2, split at qt+1
    kt0 = (code == 1) ? half : 0;
    kt1 = (code == 0) ? half : 2 * qt + 2;
  }
  const int b = bh >> 4;
  const int h = bh & 15;
  const int tid = threadIdx.x;
  const int wid = tid >> 6, lane = tid & 63;
  const int quad = lane >> 4, l16 = lane & 15;
  const int q0 = qt * 128;
  const u16* Qb = Q + ((size_t)b * SS + q0) * DD + h * DKK;
  const u16* Kb0 = K + (size_t)b * SS * DD + h * DKK;
  const u16* VTb = VT + ((size_t)(b * HH + h)) * DKK * SS;
  const int* mrow = mask + (size_t)b * SS;
  s16x8 qf[2][2];
#pragma unroll
  for (int rg = 0; rg < 2; ++rg)
#pragma unroll
    for (int ks = 0; ks < 2; ++ks)
      qf[rg][ks] = *(const s16x8*)(Qb + (size_t)(wid * 32 + rg * 16 + l16) * DD +
                                   ks * 32 + quad * 8);
  s16x8 onesf;
#pragma unroll
  for (int i = 0; i < 8; ++i) onesf[i] = (short)0x3F80;
  f32x4 oacc[2][4] = {};
  f32x4 lacc[2] = {};
  // 0.125 (1/sqrt(dk)) * log2(e); bias is 0/-1e30 so needs no prescale.
  const float c_scale = 0.18033688f;
  const bool qodd = (quad & 1) != 0;        // odd quad within its half-pair
  const bool is_hi = (lane >= 32);          // upper 32 lanes
  const bool midq = (quad == 1) || (quad == 2);  // quads needing cross-half data
  const int xaddr = (lane ^ 32) << 2;       // bpermute byte addr: pull lane^32
  const int qrow0 = q0 + wid * 32 + l16;    // + rg*16 per row-group
  // dst-lane word gather: S local-j candidate, S2 what my xor32-partner must
  // export, R the pulled value; middle quads take R, outer quads take S.
  auto mixf = [&](uint32_t vj0, uint32_t vj1) -> uint32_t {
    const uint32_t S  = is_hi ? vj1 : vj0;
    const uint32_t S2 = is_hi ? vj0 : vj1;
    const uint32_t R  = (uint32_t)__builtin_amdgcn_ds_bpermute(xaddr, (int)S2);
    return midq ? R : S;
  };
  // cooperative staging coords: 4 gload_lds per thread per tile (2 K + 2 V)
  auto stage = [&](int bufsel, int kt) {
    const u16* Kb = Kb0 + (size_t)(kt * 64) * DD;
#pragma unroll
    for (int i = 0; i < 2; ++i) {
      const int s = i * 256 + tid;
      const int row = s >> 3;
      const int cc = (s & 7) ^ (row & 7);
      async_copy16(Kb + (size_t)row * DD + cc * 8,
                   (char*)(&Klds[bufsel][0]) + (i * 256 + wid * 64) * 16);
    }
#pragma unroll
    for (int i = 0; i < 2; ++i) {
      const int s = i * 256 + tid;
      const int row = s >> 3;               // d
      const int cc = (s & 7) ^ (row & 7);
      async_copy16(VTb + (size_t)row * SS + kt * 64 + cc * 8,
                   (char*)(&Vt[bufsel][0]) + (i * 256 + wid * 64) * 16);
    }
  };

  stage(kt0 & 1, kt0);
  for (int kt = kt0; kt < kt1; ++kt) {
    const int cur = kt & 1;
    // per-lane mask words for k = j*16 + quad*4 + r (L1-broadcast, 4 lines/wave)
    int4 mq[4];
#pragma unroll
    for (int j = 0; j < 4; ++j)
      mq[j] = *(const int4*)(mrow + kt * 64 + j * 16 + quad * 4);
    __builtin_amdgcn_sched_barrier(0);
    // prefetch next tile into the other buffer (clamped dup on last iter; the
    // dup writes a never-read buffer and is drained by the post-loop vmcnt(0))
    const int ktn = (kt + 1 < kt1) ? kt + 1 : kt;
    stage(cur ^ 1, ktn);
    __builtin_amdgcn_sched_barrier(0);
    // Wait own oldest 8 (current tile + mask) BEFORE the barrier, so after the
    // barrier every wave's staging of buf[cur] has landed; own prefetch (4
    // newest) stays in flight across the whole step.
    asm volatile("s_waitcnt vmcnt(4)\n\ts_barrier" ::: "memory");
    f32x4 bj[4];
#pragma unroll
    for (int j = 0; j < 4; ++j) {
      bj[j][0] = mq[j].x ? 0.0f : -1e30f;
      bj[j][1] = mq[j].y ? 0.0f : -1e30f;
      bj[j][2] = mq[j].z ? 0.0f : -1e30f;
      bj[j][3] = mq[j].w ? 0.0f : -1e30f;
    }
    f32x4 st[2][4] = {};
#pragma unroll
    for (int ks = 0; ks < 2; ++ks) {
      s16x8 kf[4];
#pragma unroll
      for (int j = 0; j < 4; ++j) {
        const int R = j * 16 + l16;
        kf[j] = *(const s16x8*)&Klds[cur][(R * 8 + ((ks * 4 + quad) ^ (l16 & 7))) * 8];
      }
      // swapped: D = K·Q^T = P^T; col(l16)=q, row(quad*4+r)=k
#pragma unroll
      for (int rg = 0; rg < 2; ++rg)
#pragma unroll
        for (int j = 0; j < 4; ++j)
          st[rg][j] = __builtin_amdgcn_mfma_f32_16x16x32_bf16(kf[j], qf[rg][ks],
                                                              st[rg][j], 0, 0, 0);
    }
    const bool causal = (kt >= 2 * qt);
    uint32_t pkv[2][8];   // [rg][j*2+h]: bf16x2 of k = j*16+quad*4+{2h,2h+1}
#pragma unroll
    for (int rg = 0; rg < 2; ++rg) {
      const int qrow = qrow0 + rg * 16;
#pragma unroll
      for (int j = 0; j < 4; ++j) {
        float p[4];
#pragma unroll
        for (int r = 0; r < 4; ++r) {
          float v = __builtin_amdgcn_exp2f(st[rg][j][r] * c_scale + bj[j][r]);
          if (causal && (kt * 64 + j * 16 + quad * 4 + r) > qrow) v = 0.0f;
          p[r] = v;
        }
        pkv[rg][j * 2 + 0] = cvtpk(p[0], p[1]);
        pkv[rg][j * 2 + 1] = cvtpk(p[2], p[3]);
      }
    }
    // PV: build A-fragments in-register, then MFMA against LDS V.
#pragma unroll
    for (int ks = 0; ks < 2; ++ks) {
      const int j0 = ks * 2, j1 = ks * 2 + 1;
      s16x8 pf[2];
#pragma unroll
      for (int rg = 0; rg < 2; ++rg) {
        const uint32_t Xa0 = pkv[rg][j0 * 2 + 0], Xa1 = pkv[rg][j0 * 2 + 1];
        const uint32_t Xb0 = pkv[rg][j1 * 2 + 0], Xb1 = pkv[rg][j1 * 2 + 1];
        const uint32_t Pa0 = swz16(Xa0), Pa1 = swz16(Xa1);
        const uint32_t Pb0 = swz16(Xb0), Pb1 = swz16(Xb1);
        // canonical (even-quad, odd-quad) sources within each half-pair
        const uint32_t Ea0 = qodd ? Pa0 : Xa0, Oa0 = qodd ? Xa0 : Pa0;
        const uint32_t Ea1 = qodd ? Pa1 : Xa1, Oa1 = qodd ? Xa1 : Pa1;
        const uint32_t Eb0 = qodd ? Pb0 : Xb0, Ob0 = qodd ? Xb0 : Pb0;
        const uint32_t Eb1 = qodd ? Pb1 : Xb1, Ob1 = qodd ? Xb1 : Pb1;
        union { uint32_t w[4]; s16x8 v; } u;
        u.w[0] = mixf(Ea0, Eb0);   // k octet words: even-src h0
        u.w[1] = mixf(Ea1, Eb1);   // even-src h1
        u.w[2] = mixf(Oa0, Ob0);   // odd-src h0
        u.w[3] = mixf(Oa1, Ob1);   // odd-src h1
        pf[rg] = u.v;
      }
#pragma unroll
      for (int jt = 0; jt < 4; ++jt) {
        const int d = jt * 16 + l16;
        const s16x8 vf = *(const s16x8*)&Vt[cur][(d * 8 + ((ks * 4 + quad) ^ (d & 7))) * 8];
#pragma unroll
        for (int rg = 0; rg < 2; ++rg)
          oacc[rg][jt] = __builtin_amdgcn_mfma_f32_16x16x32_bf16(pf[rg], vf,
                                                                oacc[rg][jt], 0, 0, 0);
      }
#pragma unroll
      for (int rg = 0; rg < 2; ++rg)
        lacc[rg] = __builtin_amdgcn_mfma_f32_16x16x32_bf16(pf[rg], onesf, lacc[rg],
                                                           0, 0, 0);
    }
    // End-of-step barrier WITHOUT vmcnt drain: prefetch stays in flight.
    // All LDS reads of buf[cur] were register-consumed above.
    asm volatile("s_barrier" ::: "memory");
  }
  // Drain the final (duplicate) prefetch before LDS could be deallocated.
  asm volatile("s_waitcnt vmcnt(0)" ::: "memory");
  if (code == 2) {
    u16* Ob = O + ((size_t)b * SS + q0) * DD + h * DKK;
#pragma unroll
    for (int rg = 0; rg < 2; ++rg)
#pragma unroll
      for (int r = 0; r < 4; ++r) {
        const float inv = 1.0f / lacc[rg][r];
        const int row = wid * 32 + rg * 16 + quad * 4 + r;
#pragma unroll
        for (int jt = 0; jt < 4; ++jt)
          Ob[(size_t)row * DD + jt * 16 + l16] = f2bf(oacc[rg][jt][r] * inv);
      }
  } else {
    // split block: write unnormalized f32 partials; combine_kernel finishes.
    const int tile = (bh << 3) + (qt - 8);       // 0..511
    const int p = tile * 2 + code;
    float* Op = Opart + (size_t)p * 8192;
    float* lp = lpart + (size_t)p * 128;
#pragma unroll
    for (int rg = 0; rg < 2; ++rg)
#pragma unroll
      for (int r = 0; r < 4; ++r) {
        const int row = wid * 32 + rg * 16 + quad * 4 + r;
        if (l16 == 0) lp[row] = lacc[rg][r];
#pragma unroll
        for (int jt = 0; jt < 4; ++jt)
          Op[row * 64 + jt * 16 + l16] = oacc[rg][jt][r];
      }
  }
}

// Merge split-K partials: O = (O_a + O_b) / (l_a + l_b), write bf16.
// 512 blocks (= bh*8 + (qt-8)) x 256 threads; each thread: one row-half (32 d).
__global__ __launch_bounds__(256) void combine_kernel(
    const float* __restrict__ Opart, const float* __restrict__ lpart,
    u16* __restrict__ O) {
  const int tile = blockIdx.x;
  const int bh = tile >> 3;
  const int qt = (tile & 7) + 8;
  const int b = bh >> 4, h = bh & 15;
  const int tid = threadIdx.x;
  const int row = tid >> 1;
  const int c0 = (tid & 1) * 32;
  const float* P0 = Opart + ((size_t)tile * 2 + 0) * 8192 + row * 64 + c0;
  const float* P1 = Opart + ((size_t)tile * 2 + 1) * 8192 + row * 64 + c0;
  const float l = lpart[((size_t)tile * 2 + 0) * 128 + row] +
                  lpart[((size_t)tile * 2 + 1) * 128 + row];
  const float inv = 1.0f / l;
  u16* Ob = O + ((size_t)b * SS + qt * 128 + row) * DD + h * DKK + c0;
#pragma unroll
  for (int i = 0; i < 8; ++i) {
    const f32x4 a = *(const f32x4*)(P0 + i * 4);
    const f32x4 c = *(const f32x4*)(P1 + i * 4);
    ushort4 o;
    o.x = f2bf((a[0] + c[0]) * inv); o.y = f2bf((a[1] + c[1]) * inv);
    o.z = f2bf((a[2] + c[2]) * inv); o.w = f2bf((a[3] + c[3]) * inv);
    *(ushort4*)(Ob + i * 4) = o;
  }
}

extern "C" void kernel_launch(void* const* d_in, const int* in_sizes, int n_in,
                              void* d_out, int out_size, void* d_ws, size_t ws_size,
                              hipStream_t stream) {
  const float* xq = (const float*)d_in[0];
  const float* xk = (const float*)d_in[1];
  const float* xv = (const float*)d_in[2];
  const int* mask = (const int*)d_in[3];
  const float* Wq = (const float*)d_in[4];
  const float* Wk = (const float*)d_in[5];
  const float* Wv = (const float*)d_in[6];
  const float* Wo = (const float*)d_in[7];
  float* out = (float*)d_out;
  const size_t elems = (size_t)BB * SS * DD;       // 8388608
  const size_t welems = (size_t)DD * DD;           // 1048576
  if (ws_size >= 109051904ull) {
    u16* wsb = (u16*)d_ws;
    u16* Xq = wsb;
    u16* Wqb = wsb + 3 * elems;
    u16* Wob = Wqb + 3 * welems;
    u16* Qb = wsb + 3 * elems + 4 * welems;
    u16* Kb = Qb + elems;
    u16* Vb = Kb + elems;   // holds VT[b][h][d][s]
    u16* Ob = wsb;          // reuse Xq region (dead after QKV GEMMs)
    // Split-K partials live in dead cvt-staging regions during attention:
    // O partials: [elems, 3*elems) u16 = 33.55 MB f32 (exact fit, 512*2*8192).
    // l partials: Wqb region (dead after QKV GEMM), 131072 f32 = 0.5 MB.
    float* Opart = (float*)(wsb + elems);
    float* lpart = (float*)(wsb + 3 * elems);
    cvt_kernel<<<14336, 256, 0, stream>>>(xq, xk, xv, Wq, Wk, Wv, Wo, wsb);
    gemm_bt<false, false><<<dim3(512, 3), 256, 0, stream>>>(
        Xq, Wqb, Qb, elems, welems, elems, /*vt_seg=*/2);
    attn_kernel<1><<<1536, 256, 0, stream>>>(Qb, Kb, Vb, mask, Ob, Opart, lpart);
    combine_kernel<<<512, 256, 0, stream>>>(Opart, lpart, Ob);
    gemm_bt<false, true><<<dim3(512, 1), 256, 0, stream>>>(Ob, Wob, out, 0, 0, 0, -1);
  } else {
    // Fallback: fp32 convert-on-stage, fits 67 MB ws. Unsplit attention.
    u16* Qb = (u16*)d_ws;
    u16* Kb = Qb + elems;
    u16* Vb = Kb + elems;
    u16* Ob = Vb + elems;
    gemm_bt<true, false><<<dim3(512, 1), 256, 0, stream>>>(xq, Wq, Qb, 0, 0, 0, -1);
    gemm_bt<true, false><<<dim3(512, 1), 256, 0, stream>>>(xk, Wk, Kb, 0, 0, 0, -1);
    gemm_bt<true, false><<<dim3(512, 1), 256, 0, stream>>>(xv, Wv, Vb, 0, 0, 0, 0);
    attn_kernel<0><<<1024, 256, 0, stream>>>(Qb, Kb, Vb, mask, Ob,
                                             (float*)d_ws, (float*)d_ws);
    gemm_bt<false, true><<<dim3(512, 1), 256, 0, stream>>>(Ob, Wo, out, 0, 0, 0, -1);
  }
}

// Round 9
// 315.176 us; speedup vs baseline: 1.0530x; 1.0530x over previous
//
#include <hip/hip_runtime.h>
#include <stdint.h>

#define BB 4
#define SS 2048
#define DD 1024
#define HH 16
#define DKK 64

typedef unsigned short u16;
typedef short s16x8 __attribute__((ext_vector_type(8)));
typedef float f32x4 __attribute__((ext_vector_type(4)));

__device__ __forceinline__ void async_copy16(const void* g, void* l) {
  __builtin_amdgcn_global_load_lds(
      (const __attribute__((address_space(1))) void*)g,
      (__attribute__((address_space(3))) void*)l, 16, 0, 0);
}

__device__ __forceinline__ u16 f2bf(float f) {
  union { float f; uint32_t u; } x; x.f = f;
  uint32_t r = x.u + 0x7fffu + ((x.u >> 16) & 1u);
  return (u16)(r >> 16);
}

// packed RNE f32x2 -> bf16x2 (hardware)
__device__ __forceinline__ uint32_t cvtpk(float a, float b) {
  uint32_t d;
  asm("v_cvt_pk_bf16_f32 %0, %1, %2" : "=v"(d) : "v"(a), "v"(b));
  return d;
}

// lane ^ 16 exchange (within each 32-lane half)
__device__ __forceinline__ uint32_t swz16(uint32_t x) {
  return (uint32_t)__builtin_amdgcn_ds_swizzle((int)x, 0x401F);
}

// One-shot fp32 -> bf16 convert of xq,xk,xv then Wq,Wk,Wv,Wo into ws.
__global__ __launch_bounds__(256) void cvt_kernel(
    const float* __restrict__ x0, const float* __restrict__ x1,
    const float* __restrict__ x2, const float* __restrict__ w0,
    const float* __restrict__ w1, const float* __restrict__ w2,
    const float* __restrict__ w3, u16* __restrict__ dst) {
  const size_t base = ((size_t)blockIdx.x * 256 + threadIdx.x) * 8;
  const float* src;
  size_t off;
  if (base < 25165824ull) {
    const size_t t = base >> 23;
    src = (t == 0) ? x0 : (t == 1) ? x1 : x2;
    off = base & 8388607ull;
  } else {
    const size_t r = base - 25165824ull;
    const size_t t = r >> 20;
    src = (t == 0) ? w0 : (t == 1) ? w1 : (t == 2) ? w2 : w3;
    off = r & 1048575ull;
  }
  const float4 a = *(const float4*)(src + off);
  const float4 b = *(const float4*)(src + off + 4);
  s16x8 o;
  o[0] = (short)f2bf(a.x); o[1] = (short)f2bf(a.y);
  o[2] = (short)f2bf(a.z); o[3] = (short)f2bf(a.w);
  o[4] = (short)f2bf(b.x); o[5] = (short)f2bf(b.y);
  o[6] = (short)f2bf(b.z); o[7] = (short)f2bf(b.w);
  *(s16x8*)(dst + base) = o;
}

// C[M,N] = A[M,K] @ W[N,K]^T, fp32 accum, chunk-XOR-swizzled LDS (conflict-free
// b128 frag reads). seg = blockIdx.y. If seg == vt_seg, epilogue writes output
// transposed per-head: VT[b][h][d][s] (ushort4 = 4 contiguous tokens), else
// row-major (bf16 or fp32 per OUT_F32).
// T1 XCD swizzle: 512 x-blocks, 8 XCDs -> swz groups 64 consecutive tiles per
// XCD so the 2MB W-panel is reused 64x and each A-tile 8x within one L2.
template <bool IN_F32, bool OUT_F32>
__global__ __launch_bounds__(256, 3) void gemm_bt(
    const void* __restrict__ Ap, const void* __restrict__ Bp, void* __restrict__ Cp,
    size_t asegstride, size_t bsegstride, size_t csegstride, int vt_seg) {
  const int K = 1024, N = 1024;
  __shared__ u16 Alds[128 * 64];
  __shared__ u16 Blds[128 * 64];
  const int tid = threadIdx.x;
  const int wid = tid >> 6, lane = tid & 63;
  const int quad = lane >> 4, l16 = lane & 15;
  const int bidx = blockIdx.x;
  const int swz = ((bidx & 7) << 6) | (bidx >> 3);   // bijective, 512 % 8 == 0
  const int mtile = swz >> 3;
  const int ntile = swz & 7;
  const int wm = wid >> 1, wn = wid & 1;
  const int seg = blockIdx.y;
  f32x4 acc[4][4] = {};
  for (int kb = 0; kb < K; kb += 64) {
    if constexpr (IN_F32) {
      const float* Af = (const float*)Ap + seg * asegstride + (size_t)mtile * 128 * K;
      const float* Bf = (const float*)Bp + seg * bsegstride + (size_t)ntile * 128 * K;
#pragma unroll
      for (int i = 0; i < 8; ++i) {
        const int c = i * 256 + tid;
        const int row = c >> 4, g = c & 15;
        const int cc = g >> 1, h = g & 1;
        const int sl = row * 8 + (cc ^ (row & 7));
        {
          const float4 v = *(const float4*)(Af + (size_t)row * K + kb + g * 4);
          ushort4 o;
          o.x = f2bf(v.x); o.y = f2bf(v.y); o.z = f2bf(v.z); o.w = f2bf(v.w);
          *(ushort4*)&Alds[sl * 8 + h * 4] = o;
        }
        {
          const float4 v = *(const float4*)(Bf + (size_t)row * K + kb + g * 4);
          ushort4 o;
          o.x = f2bf(v.x); o.y = f2bf(v.y); o.z = f2bf(v.z); o.w = f2bf(v.w);
          *(ushort4*)&Blds[sl * 8 + h * 4] = o;
        }
      }
    } else {
      const u16* Ab = (const u16*)Ap + seg * asegstride + (size_t)mtile * 128 * K;
      const u16* Bb = (const u16*)Bp + seg * bsegstride + (size_t)ntile * 128 * K;
#pragma unroll
      for (int i = 0; i < 4; ++i) {
        const int s = i * 256 + tid;
        const int row = s >> 3;
        const int cc = (s & 7) ^ (row & 7);
        async_copy16(Ab + (size_t)row * K + kb + cc * 8,
                     (char*)Alds + (i * 256 + wid * 64) * 16);
        async_copy16(Bb + (size_t)row * K + kb + cc * 8,
                     (char*)Blds + (i * 256 + wid * 64) * 16);
      }
    }
    __syncthreads();
#pragma unroll
    for (int ks = 0; ks < 2; ++ks) {
      s16x8 af[4], bfr[4];
#pragma unroll
      for (int i = 0; i < 4; ++i) {
        const int R = wm * 64 + i * 16 + l16;
        af[i] = *(const s16x8*)&Alds[(R * 8 + ((ks * 4 + quad) ^ (l16 & 7))) * 8];
      }
#pragma unroll
      for (int j = 0; j < 4; ++j) {
        const int R = wn * 64 + j * 16 + l16;
        bfr[j] = *(const s16x8*)&Blds[(R * 8 + ((ks * 4 + quad) ^ (l16 & 7))) * 8];
      }
#pragma unroll
      for (int i = 0; i < 4; ++i)
#pragma unroll
        for (int j = 0; j < 4; ++j)
          acc[i][j] = __builtin_amdgcn_mfma_f32_16x16x32_bf16(af[i], bfr[j], acc[i][j], 0, 0, 0);
    }
    __syncthreads();
  }
  const int row0 = mtile * 128 + wm * 64 + quad * 4;
  const int col0 = ntile * 128 + wn * 64 + l16;
  if (seg == vt_seg) {
    // V^T epilogue: element (token, col) -> VT[(b*16+h)*64+d][s], d=col&63.
    u16* VT = (u16*)Cp + (size_t)seg * csegstride;
#pragma unroll
    for (int i = 0; i < 4; ++i)
#pragma unroll
      for (int j = 0; j < 4; ++j) {
        const int col = col0 + j * 16;
        const int row = row0 + i * 16;
        const int bb = row >> 11, s0 = row & 2047;
        const size_t dst = (((size_t)bb * HH + (col >> 6)) * DKK + (col & 63)) * SS + s0;
        ushort4 o;
        o.x = f2bf(acc[i][j][0]); o.y = f2bf(acc[i][j][1]);
        o.z = f2bf(acc[i][j][2]); o.w = f2bf(acc[i][j][3]);
        *(ushort4*)(VT + dst) = o;
      }
  } else {
#pragma unroll
    for (int i = 0; i < 4; ++i)
#pragma unroll
      for (int j = 0; j < 4; ++j)
#pragma unroll
        for (int r = 0; r < 4; ++r) {
          const size_t idx = (size_t)(row0 + i * 16 + r) * N + col0 + j * 16;
          if constexpr (OUT_F32) ((float*)Cp)[seg * csegstride + idx] = acc[i][j][r];
          else                   ((u16*)Cp)[seg * csegstride + idx] = f2bf(acc[i][j][r]);
        }
  }
}

// Flash attention: 128 q-rows/block, 4 waves x 32 q-rows, swapped QK^T (T12)
// with fully in-register P redistribution (verified R4/R6 structure, 0 bank
// conflicts, 64 VGPR). V pre-transposed per-head VT[b][h][d][s]. No-max
// softmax via exp2, l via ones-MFMA. Single-buffered staging (verified best:
// prefetch/dbuf variants regressed twice — TLP at 4 blocks/CU already hides
// staging latency). Monolithic kt-loop with runtime causal bool (the
// compile-time loop-split variant failed correctness unexplained; dropped).
// MODE 0: one block per q-tile (grid 1024), direct O write.
// MODE 1: SPLIT-K — qt>=8 tiles split into two kt-halves across two blocks
// (grid 1536, chains <= 16 steps), strict-LPT arithmetic work decode:
// w<16: qt=15-(w>>1), code=w&1 (halves, heavy first); w>=16: qt=23-w, code=2.
// No-max softmax partials combine by pure addition:
// O = (O_a + O_b) / (l_a + l_b); combine_kernel finishes.
template <int MODE>
__global__ __launch_bounds__(256, 4) void attn_kernel(
    const u16* __restrict__ Q, const u16* __restrict__ K, const u16* __restrict__ VT,
    const int* __restrict__ mask, u16* __restrict__ O,
    float* __restrict__ Opart, float* __restrict__ lpart) {
  __shared__ u16 Klds[64 * 64];    // swizzled [key][d]
  __shared__ u16 Vt[64 * 64];      // swizzled [d][key]
  __shared__ float bias[64];
  const int bid = blockIdx.x;
  int qt, kt0, kt1, code, bh;
  if constexpr (MODE == 0) {
    qt = 15 - (bid >> 6);          // heavy tiles first
    bh = bid & 63;
    code = 2;                      // always full tile
    kt0 = 0; kt1 = 2 * qt + 2;
  } else {
    bh = bid & 63;
    const int w = bid >> 6;        // 0..23, strict LPT (longest chains first)
    if (w < 16) { qt = 15 - (w >> 1); code = w & 1; }
    else        { qt = 23 - w;       code = 2; }
    const int half = qt + 1;       // ktiles = 2qt+2, split at qt+1
    kt0 = (code == 1) ? half : 0;
    kt1 = (code == 0) ? half : 2 * qt + 2;
  }
  const int b = bh >> 4;
  const int h = bh & 15;
  const int tid = threadIdx.x;
  const int wid = tid >> 6, lane = tid & 63;
  const int quad = lane >> 4, l16 = lane & 15;
  const int q0 = qt * 128;
  const u16* Qb = Q + ((size_t)b * SS + q0) * DD + h * DKK;
  const u16* Kb0 = K + (size_t)b * SS * DD + h * DKK;
  const u16* VTb = VT + ((size_t)(b * HH + h)) * DKK * SS;
  s16x8 qf[2][2];
#pragma unroll
  for (int rg = 0; rg < 2; ++rg)
#pragma unroll
    for (int ks = 0; ks < 2; ++ks)
      qf[rg][ks] = *(const s16x8*)(Qb + (size_t)(wid * 32 + rg * 16 + l16) * DD +
                                   ks * 32 + quad * 8);
  s16x8 onesf;
#pragma unroll
  for (int i = 0; i < 8; ++i) onesf[i] = (short)0x3F80;
  f32x4 oacc[2][4] = {};
  f32x4 lacc[2] = {};
  // 0.125 (1/sqrt(dk)) * log2(e); bias is 0/-1e30 so needs no prescale.
  const float c_scale = 0.18033688f;
  const bool qodd = (quad & 1) != 0;        // odd quad within its half-pair
  const bool is_hi = (lane >= 32);          // upper 32 lanes
  const bool midq = (quad == 1) || (quad == 2);  // quads needing cross-half data
  const int xaddr = (lane ^ 32) << 2;       // bpermute byte addr: pull lane^32
  const int qrow0 = q0 + wid * 32 + l16;    // + rg*16 per row-group
  // dst-lane word gather: S local-j candidate, S2 what my xor32-partner must
  // export, R the pulled value; middle quads take R, outer quads take S.
  auto mixf = [&](uint32_t vj0, uint32_t vj1) -> uint32_t {
    const uint32_t S  = is_hi ? vj1 : vj0;
    const uint32_t S2 = is_hi ? vj0 : vj1;
    const uint32_t R  = (uint32_t)__builtin_amdgcn_ds_bpermute(xaddr, (int)S2);
    return midq ? R : S;
  };
  for (int kt = kt0; kt < kt1; ++kt) {
    const u16* Kb = Kb0 + (size_t)(kt * 64) * DD;
#pragma unroll
    for (int i = 0; i < 2; ++i) {
      const int s = i * 256 + tid;
      const int row = s >> 3;
      const int cc = (s & 7) ^ (row & 7);
      async_copy16(Kb + (size_t)row * DD + cc * 8,
                   (char*)Klds + (i * 256 + wid * 64) * 16);
    }
#pragma unroll
    for (int i = 0; i < 2; ++i) {
      const int s = i * 256 + tid;
      const int row = s >> 3;               // d
      const int cc = (s & 7) ^ (row & 7);
      async_copy16(VTb + (size_t)row * SS + kt * 64 + cc * 8,
                   (char*)Vt + ((i * 256 + wid * 64) * 16));
    }
    if (tid < 64) bias[tid] = mask[(size_t)b * SS + kt * 64 + tid] ? 0.0f : -1e30f;
    __syncthreads();
    // bias for k = j*16 + quad*4 + r  (P^T layout: k lives in quad/r)
    f32x4 bj[4];
#pragma unroll
    for (int j = 0; j < 4; ++j) bj[j] = *(const f32x4*)&bias[j * 16 + quad * 4];
    f32x4 st[2][4] = {};
#pragma unroll
    for (int ks = 0; ks < 2; ++ks) {
      s16x8 kf[4];
#pragma unroll
      for (int j = 0; j < 4; ++j) {
        const int R = j * 16 + l16;
        kf[j] = *(const s16x8*)&Klds[(R * 8 + ((ks * 4 + quad) ^ (l16 & 7))) * 8];
      }
      // swapped: D = K·Q^T = P^T; col(l16)=q, row(quad*4+r)=k
#pragma unroll
      for (int rg = 0; rg < 2; ++rg)
#pragma unroll
        for (int j = 0; j < 4; ++j)
          st[rg][j] = __builtin_amdgcn_mfma_f32_16x16x32_bf16(kf[j], qf[rg][ks],
                                                              st[rg][j], 0, 0, 0);
    }
    const bool causal = (kt >= 2 * qt);
    uint32_t pkv[2][8];   // [rg][j*2+h]: bf16x2 of k = j*16+quad*4+{2h,2h+1}
#pragma unroll
    for (int rg = 0; rg < 2; ++rg) {
      const int qrow = qrow0 + rg * 16;
#pragma unroll
      for (int j = 0; j < 4; ++j) {
        float p[4];
#pragma unroll
        for (int r = 0; r < 4; ++r) {
          float v = __builtin_amdgcn_exp2f(st[rg][j][r] * c_scale + bj[j][r]);
          if (causal && (kt * 64 + j * 16 + quad * 4 + r) > qrow) v = 0.0f;
          p[r] = v;
        }
        pkv[rg][j * 2 + 0] = cvtpk(p[0], p[1]);
        pkv[rg][j * 2 + 1] = cvtpk(p[2], p[3]);
      }
    }
    // PV: build A-fragments in-register, then MFMA against LDS V.
#pragma unroll
    for (int ks = 0; ks < 2; ++ks) {
      const int j0 = ks * 2, j1 = ks * 2 + 1;
      s16x8 pf[2];
#pragma unroll
      for (int rg = 0; rg < 2; ++rg) {
        const uint32_t Xa0 = pkv[rg][j0 * 2 + 0], Xa1 = pkv[rg][j0 * 2 + 1];
        const uint32_t Xb0 = pkv[rg][j1 * 2 + 0], Xb1 = pkv[rg][j1 * 2 + 1];
        const uint32_t Pa0 = swz16(Xa0), Pa1 = swz16(Xa1);
        const uint32_t Pb0 = swz16(Xb0), Pb1 = swz16(Xb1);
        // canonical (even-quad, odd-quad) sources within each half-pair
        const uint32_t Ea0 = qodd ? Pa0 : Xa0, Oa0 = qodd ? Xa0 : Pa0;
        const uint32_t Ea1 = qodd ? Pa1 : Xa1, Oa1 = qodd ? Xa1 : Pa1;
        const uint32_t Eb0 = qodd ? Pb0 : Xb0, Ob0 = qodd ? Xb0 : Pb0;
        const uint32_t Eb1 = qodd ? Pb1 : Xb1, Ob1 = qodd ? Xb1 : Pb1;
        union { uint32_t w[4]; s16x8 v; } u;
        u.w[0] = mixf(Ea0, Eb0);   // k octet words: even-src h0
        u.w[1] = mixf(Ea1, Eb1);   // even-src h1
        u.w[2] = mixf(Oa0, Ob0);   // odd-src h0
        u.w[3] = mixf(Oa1, Ob1);   // odd-src h1
        pf[rg] = u.v;
      }
#pragma unroll
      for (int jt = 0; jt < 4; ++jt) {
        const int d = jt * 16 + l16;
        const s16x8 vf = *(const s16x8*)&Vt[(d * 8 + ((ks * 4 + quad) ^ (d & 7))) * 8];
#pragma unroll
        for (int rg = 0; rg < 2; ++rg)
          oacc[rg][jt] = __builtin_amdgcn_mfma_f32_16x16x32_bf16(pf[rg], vf,
                                                                oacc[rg][jt], 0, 0, 0);
      }
#pragma unroll
      for (int rg = 0; rg < 2; ++rg)
        lacc[rg] = __builtin_amdgcn_mfma_f32_16x16x32_bf16(pf[rg], onesf, lacc[rg],
                                                           0, 0, 0);
    }
    __syncthreads();
  }
  if (code == 2) {
    u16* Ob = O + ((size_t)b * SS + q0) * DD + h * DKK;
#pragma unroll
    for (int rg = 0; rg < 2; ++rg)
#pragma unroll
      for (int r = 0; r < 4; ++r) {
        const float inv = 1.0f / lacc[rg][r];
        const int row = wid * 32 + rg * 16 + quad * 4 + r;
#pragma unroll
        for (int jt = 0; jt < 4; ++jt)
          Ob[(size_t)row * DD + jt * 16 + l16] = f2bf(oacc[rg][jt][r] * inv);
      }
  } else {
    // split block: write unnormalized f32 partials; combine_kernel finishes.
    const int tile = (bh << 3) + (qt - 8);       // 0..511
    const int p = tile * 2 + code;
    float* Op = Opart + (size_t)p * 8192;
    float* lp = lpart + (size_t)p * 128;
#pragma unroll
    for (int rg = 0; rg < 2; ++rg)
#pragma unroll
      for (int r = 0; r < 4; ++r) {
        const int row = wid * 32 + rg * 16 + quad * 4 + r;
        if (l16 == 0) lp[row] = lacc[rg][r];
#pragma unroll
        for (int jt = 0; jt < 4; ++jt)
          Op[row * 64 + jt * 16 + l16] = oacc[rg][jt][r];
      }
  }
}

// Merge split-K partials: O = (O_a + O_b) / (l_a + l_b), write bf16.
// 512 blocks (= bh*8 + (qt-8)) x 256 threads; each thread: one row-half (32 d).
__global__ __launch_bounds__(256) void combine_kernel(
    const float* __restrict__ Opart, const float* __restrict__ lpart,
    u16* __restrict__ O) {
  const int tile = blockIdx.x;
  const int bh = tile >> 3;
  const int qt = (tile & 7) + 8;
  const int b = bh >> 4, h = bh & 15;
  const int tid = threadIdx.x;
  const int row = tid >> 1;
  const int c0 = (tid & 1) * 32;
  const float* P0 = Opart + ((size_t)tile * 2 + 0) * 8192 + row * 64 + c0;
  const float* P1 = Opart + ((size_t)tile * 2 + 1) * 8192 + row * 64 + c0;
  const float l = lpart[((size_t)tile * 2 + 0) * 128 + row] +
                  lpart[((size_t)tile * 2 + 1) * 128 + row];
  const float inv = 1.0f / l;
  u16* Ob = O + ((size_t)b * SS + qt * 128 + row) * DD + h * DKK + c0;
#pragma unroll
  for (int i = 0; i < 8; ++i) {
    const f32x4 a = *(const f32x4*)(P0 + i * 4);
    const f32x4 c = *(const f32x4*)(P1 + i * 4);
    ushort4 o;
    o.x = f2bf((a[0] + c[0]) * inv); o.y = f2bf((a[1] + c[1]) * inv);
    o.z = f2bf((a[2] + c[2]) * inv); o.w = f2bf((a[3] + c[3]) * inv);
    *(ushort4*)(Ob + i * 4) = o;
  }
}

extern "C" void kernel_launch(void* const* d_in, const int* in_sizes, int n_in,
                              void* d_out, int out_size, void* d_ws, size_t ws_size,
                              hipStream_t stream) {
  const float* xq = (const float*)d_in[0];
  const float* xk = (const float*)d_in[1];
  const float* xv = (const float*)d_in[2];
  const int* mask = (const int*)d_in[3];
  const float* Wq = (const float*)d_in[4];
  const float* Wk = (const float*)d_in[5];
  const float* Wv = (const float*)d_in[6];
  const float* Wo = (const float*)d_in[7];
  float* out = (float*)d_out;
  const size_t elems = (size_t)BB * SS * DD;       // 8388608
  const size_t welems = (size_t)DD * DD;           // 1048576
  if (ws_size >= 109051904ull) {
    u16* wsb = (u16*)d_ws;
    u16* Xq = wsb;
    u16* Wqb = wsb + 3 * elems;
    u16* Wob = Wqb + 3 * welems;
    u16* Qb = wsb + 3 * elems + 4 * welems;
    u16* Kb = Qb + elems;
    u16* Vb = Kb + elems;   // holds VT[b][h][d][s]
    u16* Ob = wsb;          // reuse Xq region (dead after QKV GEMMs)
    // Split-K partials live in dead cvt-staging regions during attention:
    // O partials: [elems, 3*elems) u16 = 32 MiB f32 (exact fit, 512*2*8192).
    // l partials: Wqb region (dead after QKV GEMM), 131072 f32 = 0.5 MiB.
    float* Opart = (float*)(wsb + elems);
    float* lpart = (float*)(wsb + 3 * elems);
    cvt_kernel<<<14336, 256, 0, stream>>>(xq, xk, xv, Wq, Wk, Wv, Wo, wsb);
    gemm_bt<false, false><<<dim3(512, 3), 256, 0, stream>>>(
        Xq, Wqb, Qb, elems, welems, elems, /*vt_seg=*/2);
    attn_kernel<1><<<1536, 256, 0, stream>>>(Qb, Kb, Vb, mask, Ob, Opart, lpart);
    combine_kernel<<<512, 256, 0, stream>>>(Opart, lpart, Ob);
    gemm_bt<false, true><<<dim3(512, 1), 256, 0, stream>>>(Ob, Wob, out, 0, 0, 0, -1);
  } else {
    // Fallback: fp32 convert-on-stage, fits 67 MB ws. Unsplit attention.
    u16* Qb = (u16*)d_ws;
    u16* Kb = Qb + elems;
    u16* Vb = Kb + elems;
    u16* Ob = Vb + elems;
    gemm_bt<true, false><<<dim3(512, 1), 256, 0, stream>>>(xq, Wq, Qb, 0, 0, 0, -1);
    gemm_bt<true, false><<<dim3(512, 1), 256, 0, stream>>>(xk, Wk, Kb, 0, 0, 0, -1);
    gemm_bt<true, false><<<dim3(512, 1), 256, 0, stream>>>(xv, Wv, Vb, 0, 0, 0, 0);
    attn_kernel<0><<<1024, 256, 0, stream>>>(Qb, Kb, Vb, mask, Ob,
                                             (float*)d_ws, (float*)d_ws);
    gemm_bt<false, true><<<dim3(512, 1), 256, 0, stream>>>(Ob, Wo, out, 0, 0, 0, -1);
  }
}

// Round 10
// 310.452 us; speedup vs baseline: 1.0690x; 1.0152x over previous
//
#include <hip/hip_runtime.h>
#include <stdint.h>

#define BB 4
#define SS 2048
#define DD 1024
#define HH 16
#define DKK 64

typedef unsigned short u16;
typedef short s16x8 __attribute__((ext_vector_type(8)));
typedef float f32x4 __attribute__((ext_vector_type(4)));

__device__ __forceinline__ void async_copy16(const void* g, void* l) {
  __builtin_amdgcn_global_load_lds(
      (const __attribute__((address_space(1))) void*)g,
      (__attribute__((address_space(3))) void*)l, 16, 0, 0);
}

__device__ __forceinline__ u16 f2bf(float f) {
  union { float f; uint32_t u; } x; x.f = f;
  uint32_t r = x.u + 0x7fffu + ((x.u >> 16) & 1u);
  return (u16)(r >> 16);
}

// packed RNE f32x2 -> bf16x2 (hardware)
__device__ __forceinline__ uint32_t cvtpk(float a, float b) {
  uint32_t d;
  asm("v_cvt_pk_bf16_f32 %0, %1, %2" : "=v"(d) : "v"(a), "v"(b));
  return d;
}

// lane ^ 16 exchange (within each 32-lane half)
__device__ __forceinline__ uint32_t swz16(uint32_t x) {
  return (uint32_t)__builtin_amdgcn_ds_swizzle((int)x, 0x401F);
}

// One-shot fp32 -> bf16 convert of xq,xk,xv then Wq,Wk,Wv,Wo into ws.
__global__ __launch_bounds__(256) void cvt_kernel(
    const float* __restrict__ x0, const float* __restrict__ x1,
    const float* __restrict__ x2, const float* __restrict__ w0,
    const float* __restrict__ w1, const float* __restrict__ w2,
    const float* __restrict__ w3, u16* __restrict__ dst) {
  const size_t base = ((size_t)blockIdx.x * 256 + threadIdx.x) * 8;
  const float* src;
  size_t off;
  if (base < 25165824ull) {
    const size_t t = base >> 23;
    src = (t == 0) ? x0 : (t == 1) ? x1 : x2;
    off = base & 8388607ull;
  } else {
    const size_t r = base - 25165824ull;
    const size_t t = r >> 20;
    src = (t == 0) ? w0 : (t == 1) ? w1 : (t == 2) ? w2 : w3;
    off = r & 1048575ull;
  }
  const float4 a = *(const float4*)(src + off);
  const float4 b = *(const float4*)(src + off + 4);
  s16x8 o;
  o[0] = (short)f2bf(a.x); o[1] = (short)f2bf(a.y);
  o[2] = (short)f2bf(a.z); o[3] = (short)f2bf(a.w);
  o[4] = (short)f2bf(b.x); o[5] = (short)f2bf(b.y);
  o[6] = (short)f2bf(b.z); o[7] = (short)f2bf(b.w);
  *(s16x8*)(dst + base) = o;
}

// C[M,N] = A[M,K] @ W[N,K]^T, fp32 accum, chunk-XOR-swizzled LDS (conflict-free
// b128 frag reads). seg = blockIdx.y. If seg == vt_seg, epilogue writes output
// transposed per-head: VT[b][h][d][s] (ushort4 = 4 contiguous tokens), else
// row-major (bf16 or fp32 per OUT_F32).
// T1 XCD swizzle: 512 x-blocks, 8 XCDs -> swz groups 64 consecutive tiles per
// XCD so the 2MB W-panel is reused 64x and each A-tile 8x within one L2.
template <bool IN_F32, bool OUT_F32>
__global__ __launch_bounds__(256, 3) void gemm_bt(
    const void* __restrict__ Ap, const void* __restrict__ Bp, void* __restrict__ Cp,
    size_t asegstride, size_t bsegstride, size_t csegstride, int vt_seg) {
  const int K = 1024, N = 1024;
  __shared__ u16 Alds[128 * 64];
  __shared__ u16 Blds[128 * 64];
  const int tid = threadIdx.x;
  const int wid = tid >> 6, lane = tid & 63;
  const int quad = lane >> 4, l16 = lane & 15;
  const int bidx = blockIdx.x;
  const int swz = ((bidx & 7) << 6) | (bidx >> 3);   // bijective, 512 % 8 == 0
  const int mtile = swz >> 3;
  const int ntile = swz & 7;
  const int wm = wid >> 1, wn = wid & 1;
  const int seg = blockIdx.y;
  f32x4 acc[4][4] = {};
  for (int kb = 0; kb < K; kb += 64) {
    if constexpr (IN_F32) {
      const float* Af = (const float*)Ap + seg * asegstride + (size_t)mtile * 128 * K;
      const float* Bf = (const float*)Bp + seg * bsegstride + (size_t)ntile * 128 * K;
#pragma unroll
      for (int i = 0; i < 8; ++i) {
        const int c = i * 256 + tid;
        const int row = c >> 4, g = c & 15;
        const int cc = g >> 1, h = g & 1;
        const int sl = row * 8 + (cc ^ (row & 7));
        {
          const float4 v = *(const float4*)(Af + (size_t)row * K + kb + g * 4);
          ushort4 o;
          o.x = f2bf(v.x); o.y = f2bf(v.y); o.z = f2bf(v.z); o.w = f2bf(v.w);
          *(ushort4*)&Alds[sl * 8 + h * 4] = o;
        }
        {
          const float4 v = *(const float4*)(Bf + (size_t)row * K + kb + g * 4);
          ushort4 o;
          o.x = f2bf(v.x); o.y = f2bf(v.y); o.z = f2bf(v.z); o.w = f2bf(v.w);
          *(ushort4*)&Blds[sl * 8 + h * 4] = o;
        }
      }
    } else {
      const u16* Ab = (const u16*)Ap + seg * asegstride + (size_t)mtile * 128 * K;
      const u16* Bb = (const u16*)Bp + seg * bsegstride + (size_t)ntile * 128 * K;
#pragma unroll
      for (int i = 0; i < 4; ++i) {
        const int s = i * 256 + tid;
        const int row = s >> 3;
        const int cc = (s & 7) ^ (row & 7);
        async_copy16(Ab + (size_t)row * K + kb + cc * 8,
                     (char*)Alds + (i * 256 + wid * 64) * 16);
        async_copy16(Bb + (size_t)row * K + kb + cc * 8,
                     (char*)Blds + (i * 256 + wid * 64) * 16);
      }
    }
    __syncthreads();
#pragma unroll
    for (int ks = 0; ks < 2; ++ks) {
      s16x8 af[4], bfr[4];
#pragma unroll
      for (int i = 0; i < 4; ++i) {
        const int R = wm * 64 + i * 16 + l16;
        af[i] = *(const s16x8*)&Alds[(R * 8 + ((ks * 4 + quad) ^ (l16 & 7))) * 8];
      }
#pragma unroll
      for (int j = 0; j < 4; ++j) {
        const int R = wn * 64 + j * 16 + l16;
        bfr[j] = *(const s16x8*)&Blds[(R * 8 + ((ks * 4 + quad) ^ (l16 & 7))) * 8];
      }
#pragma unroll
      for (int i = 0; i < 4; ++i)
#pragma unroll
        for (int j = 0; j < 4; ++j)
          acc[i][j] = __builtin_amdgcn_mfma_f32_16x16x32_bf16(af[i], bfr[j], acc[i][j], 0, 0, 0);
    }
    __syncthreads();
  }
  const int row0 = mtile * 128 + wm * 64 + quad * 4;
  const int col0 = ntile * 128 + wn * 64 + l16;
  if (seg == vt_seg) {
    // V^T epilogue: element (token, col) -> VT[(b*16+h)*64+d][s], d=col&63.
    u16* VT = (u16*)Cp + (size_t)seg * csegstride;
#pragma unroll
    for (int i = 0; i < 4; ++i)
#pragma unroll
      for (int j = 0; j < 4; ++j) {
        const int col = col0 + j * 16;
        const int row = row0 + i * 16;
        const int bb = row >> 11, s0 = row & 2047;
        const size_t dst = (((size_t)bb * HH + (col >> 6)) * DKK + (col & 63)) * SS + s0;
        ushort4 o;
        o.x = f2bf(acc[i][j][0]); o.y = f2bf(acc[i][j][1]);
        o.z = f2bf(acc[i][j][2]); o.w = f2bf(acc[i][j][3]);
        *(ushort4*)(VT + dst) = o;
      }
  } else {
#pragma unroll
    for (int i = 0; i < 4; ++i)
#pragma unroll
      for (int j = 0; j < 4; ++j)
#pragma unroll
        for (int r = 0; r < 4; ++r) {
          const size_t idx = (size_t)(row0 + i * 16 + r) * N + col0 + j * 16;
          if constexpr (OUT_F32) ((float*)Cp)[seg * csegstride + idx] = acc[i][j][r];
          else                   ((u16*)Cp)[seg * csegstride + idx] = f2bf(acc[i][j][r]);
        }
  }
}

// Flash attention: 128 q-rows/block, 4 waves x 32 q-rows, swapped QK^T (T12)
// with fully in-register P redistribution (verified R4/R6 structure, 0 bank
// conflicts, 64 VGPR). V pre-transposed per-head VT[b][h][d][s]. No-max
// softmax via exp2, l via ones-MFMA. Single-buffered staging (verified best:
// prefetch/dbuf variants regressed twice — TLP at 4 blocks/CU already hides
// staging latency).
// BIAS HOIST: the whole chain's mask->bias is converted ONCE into LDS in the
// prologue (same total bytes, zero per-step VMEM), removing the per-step
// global mask load + convert from the barrier-bounded critical path.
// MODE 0: one block per q-tile (grid 1024), direct O write.
// MODE 1: SPLIT-K — qt>=8 tiles split into two kt-halves across two blocks
// (grid 1536, chains <= 16 steps), R6 bit-packed work table (interleaves the
// long FULL tiles qt=7..4 into the first 1024 resident blocks so the queued
// tail holds only short chains — do NOT "simplify" to halves-first order,
// that regressed 10 us in R9). No-max softmax partials combine by pure
// addition: O = (O_a + O_b) / (l_a + l_b); combine_kernel finishes.
template <int MODE>
__global__ __launch_bounds__(256, 4) void attn_kernel(
    const u16* __restrict__ Q, const u16* __restrict__ K, const u16* __restrict__ VT,
    const int* __restrict__ mask, u16* __restrict__ O,
    float* __restrict__ Opart, float* __restrict__ lpart) {
  __shared__ u16 Klds[64 * 64];    // swizzled [key][d]
  __shared__ u16 Vt[64 * 64];      // swizzled [d][key]
  __shared__ float bias[2048];     // whole-chain bias (<=32 steps x 64 keys)
  const int bid = blockIdx.x;
  int qt, kt0, kt1, code, bh;
  if constexpr (MODE == 0) {
    qt = 15 - (bid >> 6);          // heavy tiles first
    bh = bid & 63;
    code = 2;                      // always full tile
    kt0 = 0; kt1 = 2 * qt + 2;
  } else {
    bh = bid & 63;
    const int w = bid >> 6;        // 0..23, heavy-first work items (R6 table)
    const int wsel = w >> 3, wo = w & 7;
    // qt nibbles, low-first: {15,15,7,14,14,6,13,13|12,12,5,11,11,10,10,4|9,9,8,8,3,2,1,0}
    const uint32_t qw = (wsel == 0) ? 0xDD6EE7FFu : (wsel == 1) ? 0x4AABB5CCu : 0x01238899u;
    // split codes (2b): 0=first half, 1=second half, 2=full tile
    const uint32_t sw = (wsel == 0) ? 0x4924u : (wsel == 1) ? 0x9124u : 0xAA44u;
    qt = (int)((qw >> (wo * 4)) & 15u);
    code = (int)((sw >> (wo * 2)) & 3u);
    const int half = qt + 1;       // ktiles = 2qt+2, split at qt+1
    kt0 = (code == 1) ? half : 0;
    kt1 = (code == 0) ? half : 2 * qt + 2;
  }
  const int b = bh >> 4;
  const int h = bh & 15;
  const int tid = threadIdx.x;
  const int wid = tid >> 6, lane = tid & 63;
  const int quad = lane >> 4, l16 = lane & 15;
  const int q0 = qt * 128;
  const u16* Qb = Q + ((size_t)b * SS + q0) * DD + h * DKK;
  const u16* Kb0 = K + (size_t)b * SS * DD + h * DKK;
  const u16* VTb = VT + ((size_t)(b * HH + h)) * DKK * SS;
  const int* mrow = mask + (size_t)b * SS + kt0 * 64;
  // Prologue: convert this chain's mask range to bias once (<=4 ints/thread).
  const int nbias = (kt1 - kt0) * 64;
  for (int i = tid; i < nbias; i += 256)
    bias[i] = mrow[i] ? 0.0f : -1e30f;
  s16x8 qf[2][2];
#pragma unroll
  for (int rg = 0; rg < 2; ++rg)
#pragma unroll
    for (int ks = 0; ks < 2; ++ks)
      qf[rg][ks] = *(const s16x8*)(Qb + (size_t)(wid * 32 + rg * 16 + l16) * DD +
                                   ks * 32 + quad * 8);
  s16x8 onesf;
#pragma unroll
  for (int i = 0; i < 8; ++i) onesf[i] = (short)0x3F80;
  f32x4 oacc[2][4] = {};
  f32x4 lacc[2] = {};
  // 0.125 (1/sqrt(dk)) * log2(e); bias is 0/-1e30 so needs no prescale.
  const float c_scale = 0.18033688f;
  const bool qodd = (quad & 1) != 0;        // odd quad within its half-pair
  const bool is_hi = (lane >= 32);          // upper 32 lanes
  const bool midq = (quad == 1) || (quad == 2);  // quads needing cross-half data
  const int xaddr = (lane ^ 32) << 2;       // bpermute byte addr: pull lane^32
  const int qrow0 = q0 + wid * 32 + l16;    // + rg*16 per row-group
  // dst-lane word gather: S local-j candidate, S2 what my xor32-partner must
  // export, R the pulled value; middle quads take R, outer quads take S.
  auto mixf = [&](uint32_t vj0, uint32_t vj1) -> uint32_t {
    const uint32_t S  = is_hi ? vj1 : vj0;
    const uint32_t S2 = is_hi ? vj0 : vj1;
    const uint32_t R  = (uint32_t)__builtin_amdgcn_ds_bpermute(xaddr, (int)S2);
    return midq ? R : S;
  };
  for (int kt = kt0; kt < kt1; ++kt) {
    const u16* Kb = Kb0 + (size_t)(kt * 64) * DD;
#pragma unroll
    for (int i = 0; i < 2; ++i) {
      const int s = i * 256 + tid;
      const int row = s >> 3;
      const int cc = (s & 7) ^ (row & 7);
      async_copy16(Kb + (size_t)row * DD + cc * 8,
                   (char*)Klds + (i * 256 + wid * 64) * 16);
    }
#pragma unroll
    for (int i = 0; i < 2; ++i) {
      const int s = i * 256 + tid;
      const int row = s >> 3;               // d
      const int cc = (s & 7) ^ (row & 7);
      async_copy16(VTb + (size_t)row * SS + kt * 64 + cc * 8,
                   (char*)Vt + ((i * 256 + wid * 64) * 16));
    }
    __syncthreads();
    // bias for k = j*16 + quad*4 + r  (P^T layout: k lives in quad/r)
    const float* bst = &bias[(kt - kt0) * 64];
    f32x4 bj[4];
#pragma unroll
    for (int j = 0; j < 4; ++j) bj[j] = *(const f32x4*)&bst[j * 16 + quad * 4];
    f32x4 st[2][4] = {};
#pragma unroll
    for (int ks = 0; ks < 2; ++ks) {
      s16x8 kf[4];
#pragma unroll
      for (int j = 0; j < 4; ++j) {
        const int R = j * 16 + l16;
        kf[j] = *(const s16x8*)&Klds[(R * 8 + ((ks * 4 + quad) ^ (l16 & 7))) * 8];
      }
      // swapped: D = K·Q^T = P^T; col(l16)=q, row(quad*4+r)=k
#pragma unroll
      for (int rg = 0; rg < 2; ++rg)
#pragma unroll
        for (int j = 0; j < 4; ++j)
          st[rg][j] = __builtin_amdgcn_mfma_f32_16x16x32_bf16(kf[j], qf[rg][ks],
                                                              st[rg][j], 0, 0, 0);
    }
    const bool causal = (kt >= 2 * qt);
    uint32_t pkv[2][8];   // [rg][j*2+h]: bf16x2 of k = j*16+quad*4+{2h,2h+1}
#pragma unroll
    for (int rg = 0; rg < 2; ++rg) {
      const int qrow = qrow0 + rg * 16;
#pragma unroll
      for (int j = 0; j < 4; ++j) {
        float p[4];
#pragma unroll
        for (int r = 0; r < 4; ++r) {
          float v = __builtin_amdgcn_exp2f(st[rg][j][r] * c_scale + bj[j][r]);
          if (causal && (kt * 64 + j * 16 + quad * 4 + r) > qrow) v = 0.0f;
          p[r] = v;
        }
        pkv[rg][j * 2 + 0] = cvtpk(p[0], p[1]);
        pkv[rg][j * 2 + 1] = cvtpk(p[2], p[3]);
      }
    }
    // PV: build A-fragments in-register, then MFMA against LDS V.
#pragma unroll
    for (int ks = 0; ks < 2; ++ks) {
      const int j0 = ks * 2, j1 = ks * 2 + 1;
      s16x8 pf[2];
#pragma unroll
      for (int rg = 0; rg < 2; ++rg) {
        const uint32_t Xa0 = pkv[rg][j0 * 2 + 0], Xa1 = pkv[rg][j0 * 2 + 1];
        const uint32_t Xb0 = pkv[rg][j1 * 2 + 0], Xb1 = pkv[rg][j1 * 2 + 1];
        const uint32_t Pa0 = swz16(Xa0), Pa1 = swz16(Xa1);
        const uint32_t Pb0 = swz16(Xb0), Pb1 = swz16(Xb1);
        // canonical (even-quad, odd-quad) sources within each half-pair
        const uint32_t Ea0 = qodd ? Pa0 : Xa0, Oa0 = qodd ? Xa0 : Pa0;
        const uint32_t Ea1 = qodd ? Pa1 : Xa1, Oa1 = qodd ? Xa1 : Pa1;
        const uint32_t Eb0 = qodd ? Pb0 : Xb0, Ob0 = qodd ? Xb0 : Pb0;
        const uint32_t Eb1 = qodd ? Pb1 : Xb1, Ob1 = qodd ? Xb1 : Pb1;
        union { uint32_t w[4]; s16x8 v; } u;
        u.w[0] = mixf(Ea0, Eb0);   // k octet words: even-src h0
        u.w[1] = mixf(Ea1, Eb1);   // even-src h1
        u.w[2] = mixf(Oa0, Ob0);   // odd-src h0
        u.w[3] = mixf(Oa1, Ob1);   // odd-src h1
        pf[rg] = u.v;
      }
#pragma unroll
      for (int jt = 0; jt < 4; ++jt) {
        const int d = jt * 16 + l16;
        const s16x8 vf = *(const s16x8*)&Vt[(d * 8 + ((ks * 4 + quad) ^ (d & 7))) * 8];
#pragma unroll
        for (int rg = 0; rg < 2; ++rg)
          oacc[rg][jt] = __builtin_amdgcn_mfma_f32_16x16x32_bf16(pf[rg], vf,
                                                                oacc[rg][jt], 0, 0, 0);
      }
#pragma unroll
      for (int rg = 0; rg < 2; ++rg)
        lacc[rg] = __builtin_amdgcn_mfma_f32_16x16x32_bf16(pf[rg], onesf, lacc[rg],
                                                           0, 0, 0);
    }
    __syncthreads();
  }
  if (code == 2) {
    u16* Ob = O + ((size_t)b * SS + q0) * DD + h * DKK;
#pragma unroll
    for (int rg = 0; rg < 2; ++rg)
#pragma unroll
      for (int r = 0; r < 4; ++r) {
        const float inv = 1.0f / lacc[rg][r];
        const int row = wid * 32 + rg * 16 + quad * 4 + r;
#pragma unroll
        for (int jt = 0; jt < 4; ++jt)
          Ob[(size_t)row * DD + jt * 16 + l16] = f2bf(oacc[rg][jt][r] * inv);
      }
  } else {
    // split block: write unnormalized f32 partials; combine_kernel finishes.
    const int tile = (bh << 3) + (qt - 8);       // 0..511
    const int p = tile * 2 + code;
    float* Op = Opart + (size_t)p * 8192;
    float* lp = lpart + (size_t)p * 128;
#pragma unroll
    for (int rg = 0; rg < 2; ++rg)
#pragma unroll
      for (int r = 0; r < 4; ++r) {
        const int row = wid * 32 + rg * 16 + quad * 4 + r;
        if (l16 == 0) lp[row] = lacc[rg][r];
#pragma unroll
        for (int jt = 0; jt < 4; ++jt)
          Op[row * 64 + jt * 16 + l16] = oacc[rg][jt][r];
      }
  }
}

// Merge split-K partials: O = (O_a + O_b) / (l_a + l_b), write bf16.
// 512 blocks (= bh*8 + (qt-8)) x 256 threads; each thread: one row-half (32 d).
__global__ __launch_bounds__(256) void combine_kernel(
    const float* __restrict__ Opart, const float* __restrict__ lpart,
    u16* __restrict__ O) {
  const int tile = blockIdx.x;
  const int bh = tile >> 3;
  const int qt = (tile & 7) + 8;
  const int b = bh >> 4, h = bh & 15;
  const int tid = threadIdx.x;
  const int row = tid >> 1;
  const int c0 = (tid & 1) * 32;
  const float* P0 = Opart + ((size_t)tile * 2 + 0) * 8192 + row * 64 + c0;
  const float* P1 = Opart + ((size_t)tile * 2 + 1) * 8192 + row * 64 + c0;
  const float l = lpart[((size_t)tile * 2 + 0) * 128 + row] +
                  lpart[((size_t)tile * 2 + 1) * 128 + row];
  const float inv = 1.0f / l;
  u16* Ob = O + ((size_t)b * SS + qt * 128 + row) * DD + h * DKK + c0;
#pragma unroll
  for (int i = 0; i < 8; ++i) {
    const f32x4 a = *(const f32x4*)(P0 + i * 4);
    const f32x4 c = *(const f32x4*)(P1 + i * 4);
    ushort4 o;
    o.x = f2bf((a[0] + c[0]) * inv); o.y = f2bf((a[1] + c[1]) * inv);
    o.z = f2bf((a[2] + c[2]) * inv); o.w = f2bf((a[3] + c[3]) * inv);
    *(ushort4*)(Ob + i * 4) = o;
  }
}

extern "C" void kernel_launch(void* const* d_in, const int* in_sizes, int n_in,
                              void* d_out, int out_size, void* d_ws, size_t ws_size,
                              hipStream_t stream) {
  const float* xq = (const float*)d_in[0];
  const float* xk = (const float*)d_in[1];
  const float* xv = (const float*)d_in[2];
  const int* mask = (const int*)d_in[3];
  const float* Wq = (const float*)d_in[4];
  const float* Wk = (const float*)d_in[5];
  const float* Wv = (const float*)d_in[6];
  const float* Wo = (const float*)d_in[7];
  float* out = (float*)d_out;
  const size_t elems = (size_t)BB * SS * DD;       // 8388608
  const size_t welems = (size_t)DD * DD;           // 1048576
  if (ws_size >= 109051904ull) {
    u16* wsb = (u16*)d_ws;
    u16* Xq = wsb;
    u16* Wqb = wsb + 3 * elems;
    u16* Wob = Wqb + 3 * welems;
    u16* Qb = wsb + 3 * elems + 4 * welems;
    u16* Kb = Qb + elems;
    u16* Vb = Kb + elems;   // holds VT[b][h][d][s]
    u16* Ob = wsb;          // reuse Xq region (dead after QKV GEMMs)
    // Split-K partials live in dead cvt-staging regions during attention:
    // O partials: [elems, 3*elems) u16 = 32 MiB f32 (exact fit, 512*2*8192).
    // l partials: Wqb region (dead after QKV GEMM), 131072 f32 = 0.5 MiB.
    float* Opart = (float*)(wsb + elems);
    float* lpart = (float*)(wsb + 3 * elems);
    cvt_kernel<<<14336, 256, 0, stream>>>(xq, xk, xv, Wq, Wk, Wv, Wo, wsb);
    gemm_bt<false, false><<<dim3(512, 3), 256, 0, stream>>>(
        Xq, Wqb, Qb, elems, welems, elems, /*vt_seg=*/2);
    attn_kernel<1><<<1536, 256, 0, stream>>>(Qb, Kb, Vb, mask, Ob, Opart, lpart);
    combine_kernel<<<512, 256, 0, stream>>>(Opart, lpart, Ob);
    gemm_bt<false, true><<<dim3(512, 1), 256, 0, stream>>>(Ob, Wob, out, 0, 0, 0, -1);
  } else {
    // Fallback: fp32 convert-on-stage, fits 67 MB ws. Unsplit attention.
    u16* Qb = (u16*)d_ws;
    u16* Kb = Qb + elems;
    u16* Vb = Kb + elems;
    u16* Ob = Vb + elems;
    gemm_bt<true, false><<<dim3(512, 1), 256, 0, stream>>>(xq, Wq, Qb, 0, 0, 0, -1);
    gemm_bt<true, false><<<dim3(512, 1), 256, 0, stream>>>(xk, Wk, Kb, 0, 0, 0, -1);
    gemm_bt<true, false><<<dim3(512, 1), 256, 0, stream>>>(xv, Wv, Vb, 0, 0, 0, 0);
    attn_kernel<0><<<1024, 256, 0, stream>>>(Qb, Kb, Vb, mask, Ob,
                                             (float*)d_ws, (float*)d_ws);
    gemm_bt<false, true><<<dim3(512, 1), 256, 0, stream>>>(Ob, Wo, out, 0, 0, 0, -1);
  }
}